// Round 5
// baseline (341.164 us; speedup 1.0000x reference)
//
#include <hip/hip_runtime.h>
#include <hip/hip_bf16.h>
#include <stdint.h>

// B=2, S=2048, D=1024, H=16, DK=64
typedef __bf16 bf16x8 __attribute__((ext_vector_type(8)));
typedef float f32x4 __attribute__((ext_vector_type(4)));
typedef float f32x16 __attribute__((ext_vector_type(16)));

#define QSCALE 0.1803368801111244f  // (1/8) * log2(e): softmax via exp2

__device__ __forceinline__ void gld16(const void* g, void* l) {
  // async global->LDS, 16B/lane. LDS dest must be wave-uniform base + lane*16.
  __builtin_amdgcn_global_load_lds(
      (__attribute__((address_space(1))) void*)(uintptr_t)(g),
      (__attribute__((address_space(3))) void*)(l), 16, 0, 0);
}

__device__ __forceinline__ uint32_t pk_bf16(float a, float b) {
  union { __bf16 h[2]; uint32_t u; } t;
  t.h[0] = (__bf16)a; t.h[1] = (__bf16)b;
  return t.u;
}

// ---------------- cast f32 -> bf16 (7 tensors, one launch) ----------------
struct CastArgs {
  const float* src[7];
  __bf16* dst[7];
  int n[7];
};

__global__ __launch_bounds__(256) void cast_bf16_kernel(CastArgs a) {
  const int t = blockIdx.y;
  const int i = (blockIdx.x * 256 + threadIdx.x) * 8;
  if (i >= a.n[t]) return;
  const float4* s = (const float4*)(a.src[t] + i);
  float4 v0 = s[0], v1 = s[1];
  bf16x8 o;
  o[0] = (__bf16)v0.x; o[1] = (__bf16)v0.y; o[2] = (__bf16)v0.z; o[3] = (__bf16)v0.w;
  o[4] = (__bf16)v1.x; o[5] = (__bf16)v1.y; o[6] = (__bf16)v1.z; o[7] = (__bf16)v1.w;
  *(bf16x8*)(a.dst[t] + i) = o;
}

// ---------------- fused Q/K/V projection GEMM ----------------
// z=0: Q = xq @ Wq^T (scale QSCALE) -> [b][h][s][dk]
// z=1: K = xk @ Wk^T               -> [b][h][s][dk]
// z=2: V^T = Wv @ xv^T             -> [b][h][dk][s]
struct QkvArgs {
  const __bf16* A[3];
  const __bf16* B[3];
  const float* bias[3];
  __bf16* out[3];
};

__global__ __launch_bounds__(256) void qkv_gemm(QkvArgs args) {
  __shared__ __align__(16) __bf16 As[128 * 32];
  __shared__ __align__(16) __bf16 Bs[128 * 32];
  const int tid = threadIdx.x;
  const int z = blockIdx.y;
  const int bx = blockIdx.x;
  const int m0 = (z < 2 ? (bx >> 3) : (bx & 7)) * 128;
  const int n0 = (z < 2 ? (bx & 7) : (bx >> 3)) * 128;
  const __bf16* A = args.A[z];
  const __bf16* B = args.B[z];
  const float* bias = args.bias[z];
  __bf16* out = args.out[z];
  const float scale = (z == 0) ? QSCALE : 1.0f;

  const int lane = tid & 63, wid = tid >> 6;
  const int wm = (wid & 1) * 64, wn = (wid >> 1) * 64;
  const int l16 = lane & 15, quad = lane >> 4;

  const int sc = (tid & 3) ^ ((tid >> 2) & 3);  // swizzled source chunk
  const __bf16* ga = A + (size_t)(m0 + (tid >> 2)) * 1024 + sc * 8;
  const __bf16* gb = B + (size_t)(n0 + (tid >> 2)) * 1024 + sc * 8;
  char* lA = (char*)As + tid * 16;
  char* lB = (char*)Bs + tid * 16;
  const int a_off = (wm + l16) * 64 + ((quad ^ (l16 & 3)) * 16);
  const int b_off = (wn + l16) * 64 + ((quad ^ (l16 & 3)) * 16);

  f32x4 acc[4][4] = {};

  for (int k0 = 0; k0 < 1024; k0 += 32) {
    __syncthreads();
    gld16(ga + k0, lA);
    gld16(ga + k0 + 64 * 1024, lA + 4096);
    gld16(gb + k0, lB);
    gld16(gb + k0 + 64 * 1024, lB + 4096);
    __syncthreads();
    bf16x8 af[4], bfr[4];
#pragma unroll
    for (int mi = 0; mi < 4; ++mi)
      af[mi] = *(const bf16x8*)((const char*)As + a_off + mi * 1024);
#pragma unroll
    for (int ni = 0; ni < 4; ++ni)
      bfr[ni] = *(const bf16x8*)((const char*)Bs + b_off + ni * 1024);
#pragma unroll
    for (int mi = 0; mi < 4; ++mi)
#pragma unroll
      for (int ni = 0; ni < 4; ++ni)
        acc[mi][ni] = __builtin_amdgcn_mfma_f32_16x16x32_bf16(af[mi], bfr[ni],
                                                              acc[mi][ni], 0, 0, 0);
  }

  if (z < 2) {  // token-major -> [b][h][s][dk]
#pragma unroll
    for (int ni = 0; ni < 4; ++ni) {
      const int col = n0 + wn + ni * 16 + l16;
      const int h = col >> 6, dk = col & 63;
      const float bb = bias[col];
#pragma unroll
      for (int mi = 0; mi < 4; ++mi)
#pragma unroll
        for (int r = 0; r < 4; ++r) {
          const int row = m0 + wm + mi * 16 + quad * 4 + r;
          const int b = row >> 11, s = row & 2047;
          out[((size_t)(b * 16 + h) * 2048 + s) * 64 + dk] =
              (__bf16)((acc[mi][ni][r] + bb) * scale);
        }
    }
  } else {  // V: A=W (m=feature), B=X (n=token); store Vt[b][h][dk][s]
#pragma unroll
    for (int mi = 0; mi < 4; ++mi)
#pragma unroll
      for (int r = 0; r < 4; ++r) {
        const int rowm = m0 + wm + mi * 16 + quad * 4 + r;
        const int h = rowm >> 6, dk = rowm & 63;
        const float bb = bias[rowm];
#pragma unroll
        for (int ni = 0; ni < 4; ++ni) {
          const int coln = n0 + wn + ni * 16 + l16;
          const int b = coln >> 11, s = coln & 2047;
          out[((size_t)(b * 16 + h) * 64 + dk) * 2048 + s] =
              (__bf16)(acc[mi][ni][r] + bb);
        }
      }
  }
}

// ---------------- output projection GEMM (f32 out) ----------------
__global__ __launch_bounds__(256) void gemm_out(const __bf16* __restrict__ A,
                                                const __bf16* __restrict__ B,
                                                const float* __restrict__ bias,
                                                float* __restrict__ out) {
  __shared__ __align__(16) __bf16 As[128 * 32];
  __shared__ __align__(16) __bf16 Bs[128 * 32];
  const int tid = threadIdx.x;
  const int m0 = blockIdx.y * 128;
  const int n0 = blockIdx.x * 128;
  const int lane = tid & 63, wid = tid >> 6;
  const int wm = (wid & 1) * 64, wn = (wid >> 1) * 64;
  const int l16 = lane & 15, quad = lane >> 4;

  const int sc = (tid & 3) ^ ((tid >> 2) & 3);
  const __bf16* ga = A + (size_t)(m0 + (tid >> 2)) * 1024 + sc * 8;
  const __bf16* gb = B + (size_t)(n0 + (tid >> 2)) * 1024 + sc * 8;
  char* lA = (char*)As + tid * 16;
  char* lB = (char*)Bs + tid * 16;
  const int a_off = (wm + l16) * 64 + ((quad ^ (l16 & 3)) * 16);
  const int b_off = (wn + l16) * 64 + ((quad ^ (l16 & 3)) * 16);

  f32x4 acc[4][4] = {};

  for (int k0 = 0; k0 < 1024; k0 += 32) {
    __syncthreads();
    gld16(ga + k0, lA);
    gld16(ga + k0 + 64 * 1024, lA + 4096);
    gld16(gb + k0, lB);
    gld16(gb + k0 + 64 * 1024, lB + 4096);
    __syncthreads();
    bf16x8 af[4], bfr[4];
#pragma unroll
    for (int mi = 0; mi < 4; ++mi)
      af[mi] = *(const bf16x8*)((const char*)As + a_off + mi * 1024);
#pragma unroll
    for (int ni = 0; ni < 4; ++ni)
      bfr[ni] = *(const bf16x8*)((const char*)Bs + b_off + ni * 1024);
#pragma unroll
    for (int mi = 0; mi < 4; ++mi)
#pragma unroll
      for (int ni = 0; ni < 4; ++ni)
        acc[mi][ni] = __builtin_amdgcn_mfma_f32_16x16x32_bf16(af[mi], bfr[ni],
                                                              acc[mi][ni], 0, 0, 0);
  }

#pragma unroll
  for (int ni = 0; ni < 4; ++ni) {
    const int col = n0 + wn + ni * 16 + l16;
    const float bb = bias[col];
#pragma unroll
    for (int mi = 0; mi < 4; ++mi)
#pragma unroll
      for (int r = 0; r < 4; ++r) {
        const int row = m0 + wm + mi * 16 + quad * 4 + r;
        out[(size_t)row * 1024 + col] = acc[mi][ni][r] + bb;
      }
  }
}

// ---------------- flash attention: 32x32 MFMA, S^T orientation -------------
// Qh,Kh: [b][h][s][64] bf16 (Q pre-scaled by QSCALE); Vt: [b][h][64][2048];
// gprob f32 [b][s][s]; out xb: [b][s][1024] bf16.
// 4 waves = (qw,kw) quadrants of the 64q x 64k tile. Sc^T = K·Q^T so each
// lane owns one q (lane&31); P C->B-frag transform is 4 shfl_xor(32) of
// packed bf16 pairs (no LDS). O^T = V^T·P^T accumulated per kw-half;
// kw halves combined once at the end through LDS.
__global__ __launch_bounds__(256) void attn_kernel(
    const __bf16* __restrict__ Qh, const __bf16* __restrict__ Kh,
    const __bf16* __restrict__ Vt, const float* __restrict__ gprob,
    const int* __restrict__ maskp, __bf16* __restrict__ xb) {
  __shared__ __align__(16) __bf16 Ks[64 * 64];  // [k_rel][dk], 128B rows
  __shared__ __align__(16) __bf16 Vs[64 * 64];  // [dk][k_rel], 128B rows
  __shared__ float lps[2][64];
  __shared__ unsigned long long mbits[32];

  const int tid = threadIdx.x;
  const int qt = blockIdx.x, bh = blockIdx.y;
  const int b = bh >> 4, h16 = bh & 15;
  const int q0 = qt * 64;
  const int lane = tid & 63, wid = tid >> 6;
  const int qw = wid & 1, kw = wid >> 1;
  const int l32 = lane & 31, hh = lane >> 5;
  const size_t head_off = (size_t)bh * (2048 * 64);

  const int srow = tid >> 3;               // staging row 0..31
  const int sc8 = (tid & 7) ^ (srow & 7);  // swizzled source chunk
  const int fx = l32 & 7;                  // frag-read chunk xor (row&7)

  const __bf16* gk0 = Kh + head_off + (size_t)srow * 64 + sc8 * 8;
  const __bf16* gv0 = Vt + head_off + (size_t)srow * 2048 + sc8 * 8;

  // one-time mask ballot: mbits[kt] bit j = mask[b][kt*64+j]
  {
    const int* mr = maskp + b * 2048;
#pragma unroll
    for (int t = 0; t < 8; ++t) {
      const int kt2 = wid * 8 + t;
      const unsigned long long bal = __ballot(mr[kt2 * 64 + lane] != 0);
      if (lane == 0) mbits[kt2] = bal;
    }
  }

  // Q B-frags (n=q=lane&31, k=dk=8*hh+j per 16-dk block), direct from global
  const int qrow = q0 + qw * 32 + l32;
  bf16x8 bq[4];
  {
    const __bf16* gq = Qh + head_off + (size_t)qrow * 64 + hh * 8;
#pragma unroll
    for (int dkb = 0; dkb < 4; ++dkb) bq[dkb] = *(const bf16x8*)(gq + dkb * 16);
  }

  f32x16 o0 = {}, o1 = {};
  float lq[4] = {0.f, 0.f, 0.f, 0.f};

  // g: row q, k = kt*64 + kw*32 + 4*hh + gi*8 + 0..3 (matches C-layout regs)
  const float* gbase = gprob + ((size_t)b << 22) + (size_t)qrow * 2048 +
                       kw * 32 + hh * 4;

  for (int kt = 0; kt < 32; ++kt) {
    __syncthreads();  // previous iteration's readers done
    gld16(gk0 + kt * 4096, (char*)Ks + tid * 16);
    gld16(gk0 + kt * 4096 + 2048, (char*)Ks + 4096 + tid * 16);
    gld16(gv0 + kt * 64, (char*)Vs + tid * 16);
    gld16(gv0 + kt * 64 + 32 * 2048, (char*)Vs + 4096 + tid * 16);

    f32x4 gvv[4];
#pragma unroll
    for (int gi = 0; gi < 4; ++gi)
      gvv[gi] = *(const f32x4*)(gbase + kt * 64 + gi * 8);
    const uint32_t mu =
        (uint32_t)(mbits[kt] >> (kw * 32 + hh * 4));  // bits (e&3)+8*(e>>2)
    __syncthreads();  // staging landed (vmcnt0 drain)

    // Sc^T[k= kw*32+...][q=lane&31]: 4 chained 32x32x16 MFMAs over dk
    f32x16 ssc = {};
#pragma unroll
    for (int dkb = 0; dkb < 4; ++dkb) {
      const int row = kw * 32 + l32;
      const int cc = (2 * dkb + hh) ^ fx;
      bf16x8 ak = *(const bf16x8*)((const char*)Ks + (row << 7) + (cc << 4));
      ssc = __builtin_amdgcn_mfma_f32_32x32x16_bf16(ak, bq[dkb], ssc, 0, 0, 0);
    }

    // max-free softmax (p = 2^s), mask, lp partials, g-scale
    float pv[16];
    if (!(kt == qt && qw == kw)) {
#pragma unroll
      for (int e = 0; e < 16; ++e) {
        const int bi = (e & 3) + 8 * (e >> 2);
        float p = __builtin_exp2f(ssc[e]);
        p = ((mu >> bi) & 1) ? p : 0.f;
        lq[e >> 2] += p;
        pv[e] = p * gvv[e >> 2][e & 3];
      }
    } else {  // diagonal quadrant: k_rel31 == q31
#pragma unroll
      for (int e = 0; e < 16; ++e) {
        const int bi = (e & 3) + 8 * (e >> 2);
        float p = __builtin_exp2f(ssc[e]);
        const bool m = (((mu >> bi) & 1) != 0) || (l32 == bi + 4 * hh);
        p = m ? p : 0.f;
        lq[e >> 2] += p;
        pv[e] = p * gvv[e >> 2][e & 3];
      }
    }

    // pack bf16 pairs (k-consecutive), then half-wave exchange -> B-frags
    uint32_t pr[8];
#pragma unroll
    for (int p8 = 0; p8 < 8; ++p8) pr[p8] = pk_bf16(pv[2 * p8], pv[2 * p8 + 1]);

    bf16x8 pf[2];
#pragma unroll
    for (int ks = 0; ks < 2; ++ks) {
      const uint32_t x0 = hh ? pr[4 * ks + 0] : pr[4 * ks + 2];
      const uint32_t x1 = hh ? pr[4 * ks + 1] : pr[4 * ks + 3];
      const uint32_t s0 = (uint32_t)__shfl_xor((int)x0, 32);
      const uint32_t s1 = (uint32_t)__shfl_xor((int)x1, 32);
      union { uint32_t u[4]; bf16x8 v; } U;
      U.u[0] = hh ? s0 : pr[4 * ks + 0];
      U.u[1] = hh ? s1 : pr[4 * ks + 1];
      U.u[2] = hh ? pr[4 * ks + 2] : s0;
      U.u[3] = hh ? pr[4 * ks + 3] : s1;
      pf[ks] = U.v;
    }

    // O^T += V^T · P^T  (A = V rows dk, k-dim = this wave's kw half)
#pragma unroll
    for (int mb = 0; mb < 2; ++mb)
#pragma unroll
      for (int ks = 0; ks < 2; ++ks) {
        const int row = mb * 32 + l32;
        const int cc = (4 * kw + 2 * ks + hh) ^ fx;
        bf16x8 av = *(const bf16x8*)((const char*)Vs + (row << 7) + (cc << 4));
        if (mb == 0)
          o0 = __builtin_amdgcn_mfma_f32_32x32x16_bf16(av, pf[ks], o0, 0, 0, 0);
        else
          o1 = __builtin_amdgcn_mfma_f32_32x32x16_bf16(av, pf[ks], o1, 0, 0, 0);
      }
  }

  float lpq = (lq[0] + lq[1]) + (lq[2] + lq[3]);

  // combine kw halves through LDS (reuse Ks/Vs)
  __syncthreads();  // last iteration's Ks/Vs readers done
  if (kw == 1) {
    char* cb = (char*)(qw ? (void*)Vs : (void*)Ks);
#pragma unroll
    for (int ch = 0; ch < 8; ++ch) {
      const int mb = ch >> 2, e4 = ch & 3;
      f32x4 w;
#pragma unroll
      for (int i = 0; i < 4; ++i) w[i] = (mb ? o1 : o0)[e4 * 4 + i];
      *(f32x4*)(cb + lane * 128 + ((ch ^ (lane & 7)) << 4)) = w;
    }
    lps[qw][lane] = lpq;
  }
  __syncthreads();
  if (kw == 0) {
    const char* cb = (const char*)(qw ? (const void*)Vs : (const void*)Ks);
#pragma unroll
    for (int ch = 0; ch < 8; ++ch) {
      const int mb = ch >> 2, e4 = ch & 3;
      f32x4 w = *(const f32x4*)(cb + lane * 128 + ((ch ^ (lane & 7)) << 4));
#pragma unroll
      for (int i = 0; i < 4; ++i) {
        if (mb) o1[e4 * 4 + i] += w[i];
        else    o0[e4 * 4 + i] += w[i];
      }
    }
    lpq += lps[qw][lane];
    lpq += __shfl_xor(lpq, 32);
    const float inv = 1.f / lpq;

    // x[q][h*64+dk], dk = 32*mb + 8*rg + 4*hh + (0..3): 8B packed stores
    __bf16* xrow = xb + ((size_t)(b * 2048 + qrow)) * 1024 + h16 * 64;
#pragma unroll
    for (int mb = 0; mb < 2; ++mb)
#pragma unroll
      for (int rg = 0; rg < 4; ++rg) {
        const f32x16& oo = mb ? o1 : o0;
        uint2 ww;
        ww.x = pk_bf16(oo[rg * 4 + 0] * inv, oo[rg * 4 + 1] * inv);
        ww.y = pk_bf16(oo[rg * 4 + 2] * inv, oo[rg * 4 + 3] * inv);
        *(uint2*)(xrow + mb * 32 + rg * 8 + hh * 4) = ww;
      }
  }
}

extern "C" void kernel_launch(void* const* d_in, const int* in_sizes, int n_in,
                              void* d_out, int out_size, void* d_ws, size_t ws_size,
                              hipStream_t stream) {
  const float* query = (const float*)d_in[0];
  const float* key_  = (const float*)d_in[1];
  const float* value = (const float*)d_in[2];
  const float* gprob = (const float*)d_in[3];
  const int*   maskp = (const int*)d_in[4];
  const float* Wq = (const float*)d_in[5];
  const float* bq = (const float*)d_in[6];
  const float* Wk = (const float*)d_in[7];
  const float* bk = (const float*)d_in[8];
  const float* Wv = (const float*)d_in[9];
  const float* bv = (const float*)d_in[10];
  const float* Wo = (const float*)d_in[11];
  const float* bo = (const float*)d_in[12];

  char* ws = (char*)d_ws;
  const size_t MB = 1 << 20;
  __bf16* qb  = (__bf16*)(ws + 0 * MB);
  __bf16* kb  = (__bf16*)(ws + 8 * MB);
  __bf16* vb  = (__bf16*)(ws + 16 * MB);
  __bf16* Wqb = (__bf16*)(ws + 24 * MB);
  __bf16* Wkb = (__bf16*)(ws + 26 * MB);
  __bf16* Wvb = (__bf16*)(ws + 28 * MB);
  __bf16* Wob = (__bf16*)(ws + 30 * MB);
  __bf16* Qh  = (__bf16*)(ws + 32 * MB);
  __bf16* Kh  = (__bf16*)(ws + 40 * MB);
  __bf16* Vt  = (__bf16*)(ws + 48 * MB);
  __bf16* xb  = (__bf16*)(ws + 56 * MB);

  CastArgs ca;
  ca.src[0] = query; ca.dst[0] = qb;  ca.n[0] = 4194304;
  ca.src[1] = key_;  ca.dst[1] = kb;  ca.n[1] = 4194304;
  ca.src[2] = value; ca.dst[2] = vb;  ca.n[2] = 4194304;
  ca.src[3] = Wq;    ca.dst[3] = Wqb; ca.n[3] = 1048576;
  ca.src[4] = Wk;    ca.dst[4] = Wkb; ca.n[4] = 1048576;
  ca.src[5] = Wv;    ca.dst[5] = Wvb; ca.n[5] = 1048576;
  ca.src[6] = Wo;    ca.dst[6] = Wob; ca.n[6] = 1048576;
  cast_bf16_kernel<<<dim3(2048, 7), 256, 0, stream>>>(ca);

  QkvArgs qa;
  qa.A[0] = qb;  qa.B[0] = Wqb; qa.bias[0] = bq; qa.out[0] = Qh;
  qa.A[1] = kb;  qa.B[1] = Wkb; qa.bias[1] = bk; qa.out[1] = Kh;
  qa.A[2] = Wvb; qa.B[2] = vb;  qa.bias[2] = bv; qa.out[2] = Vt;
  qkv_gemm<<<dim3(256, 3), 256, 0, stream>>>(qa);

  attn_kernel<<<dim3(32, 32), 256, 0, stream>>>(Qh, Kh, Vt, gprob, maskp, xb);
  gemm_out<<<dim3(8, 32), 256, 0, stream>>>(xb, Wob, bo, (float*)d_out);
}